// Round 5
// baseline (624.265 us; speedup 1.0000x reference)
//
#include <hip/hip_runtime.h>
#include <hip/hip_bf16.h>
#include <math.h>

#define N_NODES 32000
#define NUM_GRAPHS 32
#define NPG 1000
#define N_EDGES 256000
#define IN_DIM 1024
#define HID 256
#define NW 528    // C width: 256 (Wl1) + 256 (Wr1) + 8 (Wla) + 8 (Wra)
#define KBH 1040  // LDS halves-stride per kb-block: 128*8 + 16 pad (2080 B = 2x1024B wave segs + 32B)

typedef _Float16 half8 __attribute__((ext_vector_type(8)));
typedef float f32x4 __attribute__((ext_vector_type(4)));

__device__ __forceinline__ void gload16(const void* g, void* l) {
  __builtin_amdgcn_global_load_lds((const __attribute__((address_space(1))) void*)g,
                                   (__attribute__((address_space(3))) void*)l, 16, 0, 0);
}

// ---------------- prep: zero scratch counters + build tiled fp16 weight buffer ----------------
// WsT2 per K-step (32 k): nb<4 chunks at nb*4096 + c*8 (c = kb*128 + nl);
// SP cols at 16384 + (kb*16 + ns)*8. 16896 halves per K-step.
__global__ __launch_bounds__(256) void prep_kernel(
    const float* __restrict__ Wl1, const float* __restrict__ Wr1,
    const float* __restrict__ Wla, const float* __restrict__ Wra,
    _Float16* __restrict__ WsT2, unsigned* __restrict__ zbuf)
{
  const int t = threadIdx.x;
  const int flat = blockIdx.y * 3 + blockIdx.x;   // 0..383
  for (int i = flat * 256 + t; i < 131584; i += 384 * 256) zbuf[i] = 0u;

  const int kslot = blockIdx.y;        // 0..127 -> k0 = kslot*8
  const int n = blockIdx.x * 256 + t;
  if (n >= NW) return;
  const int k0 = kslot * 8;
  half8 o;
#pragma unroll
  for (int i = 0; i < 8; ++i) {
    const int k = k0 + i;
    float v;
    if (n < 256)      v = Wl1[(size_t)k * 256 + n];
    else if (n < 512) v = Wr1[(size_t)k * 256 + n - 256];
    else if (n < 520) v = Wla[(size_t)k * 8 + n - 512];
    else              v = Wra[(size_t)k * 8 + n - 520];
    o[i] = (_Float16)v;
  }
  const int K = kslot >> 2, kb = kslot & 3;
  size_t off;
  if (n < 512) off = (size_t)K * 16896 + (size_t)(n >> 7) * 4096 + kb * 1024 + (n & 127) * 8;
  else         off = (size_t)K * 16896 + 16384 + kb * 128 + (n - 512) * 8;
  *(half8*)&WsT2[off] = o;
}

// ---------------- xsplit: XH = fp16(x), XL = fp16(x - XH) ----------------
__global__ __launch_bounds__(256) void xsplit(
    const float* __restrict__ x, _Float16* __restrict__ XH, _Float16* __restrict__ XL)
{
  const size_t i = ((size_t)blockIdx.x * 256 + threadIdx.x) * 8;
  float4 a = *(const float4*)(x + i);
  float4 b = *(const float4*)(x + i + 4);
  float v[8] = {a.x, a.y, a.z, a.w, b.x, b.y, b.z, b.w};
  half8 h, l;
#pragma unroll
  for (int j = 0; j < 8; ++j) {
    _Float16 hv = (_Float16)v[j];
    h[j] = hv;
    l[j] = (_Float16)(v[j] - (float)hv);
  }
  *(half8*)&XH[i] = h;
  *(half8*)&XL[i] = l;
}

// ---------------- MFMA GEMM: C[32000,528](fp16) = x @ [Wl1|Wr1|Wla|Wra], split-fp16 ----------------
// Pure global_load_lds staging (AH, AL, B). 1250 blocks = 250 m-panels x 5 nb.
// LDS per stream: 4 kb-blocks at 2080B stride (each = 2 contiguous 1024B wave segments).
__global__ __launch_bounds__(256) void gemm_mfma(
    const _Float16* __restrict__ XH, const _Float16* __restrict__ XL,
    const _Float16* __restrict__ WsT2, _Float16* __restrict__ C)
{
  const int orig = blockIdx.x;
  const int xcd = orig & 7, idx = orig >> 3;
  // bijective XCD swizzle, nwg=1250: q=156, r=2
  const int g = (xcd < 2 ? xcd * 157 : 314 + (xcd - 2) * 156) + idx;
  const int pm = g / 5, nb = g % 5;
  const int m0 = pm * 128;

  __shared__ _Float16 AH[4 * KBH];
  __shared__ _Float16 AL[4 * KBH];
  __shared__ _Float16 Bs[4 * KBH];

  const int tid = threadIdx.x;
  const int w = tid >> 6, l = tid & 63;
  const int wr = w >> 1, wc = w & 1;
  const int r16 = l & 15, kb4 = l >> 4;

  // A staging: chunk c (0..511): kb = c>>7, row q = c&127; seg0: c=tid, seg1: c=tid+256
  const int q0 = tid & 127, kb0 = tid >> 7;
  const int q1 = q0, kb1 = kb0 + 2;
  const int lpA0 = kb0 * KBH + q0 * 8;
  const int lpA1 = kb1 * KBH + q1 * 8;
  const _Float16* gah0 = XH + (size_t)(m0 + q0) * IN_DIM + kb0 * 8;
  const _Float16* gah1 = XH + (size_t)(m0 + q1) * IN_DIM + kb1 * 8;
  const _Float16* gal0 = XL + (size_t)(m0 + q0) * IN_DIM + kb0 * 8;
  const _Float16* gal1 = XL + (size_t)(m0 + q1) * IN_DIM + kb1 * 8;

  if (nb < 4) {
    // B staging: chunk c: kb = c>>7, col nl = c&127
    const int lpB0 = (tid >> 7) * KBH + (tid & 127) * 8;
    const int lpB1 = ((tid + 256) >> 7) * KBH + ((tid + 256) & 127) * 8;
    const _Float16* gb0 = WsT2 + nb * 4096 + tid * 8;
    const _Float16* gb1 = WsT2 + nb * 4096 + (tid + 256) * 8;

    f32x4 acc[4][4] = {};
    for (int ks = 0; ks < 32; ++ks) {
      __syncthreads();
      gload16(gah0 + ks * 32, &AH[lpA0]);
      gload16(gah1 + ks * 32, &AH[lpA1]);
      gload16(gal0 + ks * 32, &AL[lpA0]);
      gload16(gal1 + ks * 32, &AL[lpA1]);
      gload16(gb0 + (size_t)ks * 16896, &Bs[lpB0]);
      gload16(gb1 + (size_t)ks * 16896, &Bs[lpB1]);
      __syncthreads();

      half8 bf[4];
#pragma unroll
      for (int n = 0; n < 4; ++n)
        bf[n] = *(half8*)&Bs[kb4 * KBH + (wc * 64 + n * 16 + r16) * 8];
#pragma unroll
      for (int m = 0; m < 4; ++m) {
        half8 ah = *(half8*)&AH[kb4 * KBH + (wr * 64 + m * 16 + r16) * 8];
        half8 al = *(half8*)&AL[kb4 * KBH + (wr * 64 + m * 16 + r16) * 8];
#pragma unroll
        for (int n = 0; n < 4; ++n) {
          acc[m][n] = __builtin_amdgcn_mfma_f32_16x16x32_f16(ah, bf[n], acc[m][n], 0, 0, 0);
          acc[m][n] = __builtin_amdgcn_mfma_f32_16x16x32_f16(al, bf[n], acc[m][n], 0, 0, 0);
        }
      }
    }
    const int crow0 = m0 + wr * 64 + ((l >> 4) << 2);
    const int ccol0 = nb * 128 + wc * 64 + r16;
#pragma unroll
    for (int m = 0; m < 4; ++m)
#pragma unroll
      for (int n = 0; n < 4; ++n)
#pragma unroll
        for (int r = 0; r < 4; ++r)
          C[(size_t)(crow0 + m * 16 + r) * NW + ccol0 + n * 16] = (_Float16)acc[m][n][r];
  } else {
    // SP block: 16 cols (512..527); B tile = 64 chunks -> one wave-write (tid<64), linear LDS
    const _Float16* gb0 = WsT2 + 16384 + tid * 8;

    f32x4 acc2[2] = {};
    for (int ks = 0; ks < 32; ++ks) {
      __syncthreads();
      gload16(gah0 + ks * 32, &AH[lpA0]);
      gload16(gah1 + ks * 32, &AH[lpA1]);
      gload16(gal0 + ks * 32, &AL[lpA0]);
      gload16(gal1 + ks * 32, &AL[lpA1]);
      if (tid < 64) gload16(gb0 + (size_t)ks * 16896, &Bs[tid * 8]);
      __syncthreads();

      half8 bf = *(half8*)&Bs[(kb4 * 16 + r16) * 8];
#pragma unroll
      for (int m = 0; m < 2; ++m) {
        half8 ah = *(half8*)&AH[kb4 * KBH + (w * 32 + m * 16 + r16) * 8];
        half8 al = *(half8*)&AL[kb4 * KBH + (w * 32 + m * 16 + r16) * 8];
        acc2[m] = __builtin_amdgcn_mfma_f32_16x16x32_f16(ah, bf, acc2[m], 0, 0, 0);
        acc2[m] = __builtin_amdgcn_mfma_f32_16x16x32_f16(al, bf, acc2[m], 0, 0, 0);
      }
    }
    const int crow0 = m0 + w * 32 + ((l >> 4) << 2);
    const int ccol0 = 512 + r16;
#pragma unroll
    for (int m = 0; m < 2; ++m)
#pragma unroll
      for (int r = 0; r < 4; ++r)
        C[(size_t)(crow0 + m * 16 + r) * NW + ccol0] = (_Float16)acc2[m][r];
  }
}

// ---------------- CSR build ----------------
__global__ void count_deg(const int* __restrict__ dst, int* __restrict__ deg) {
  int e = blockIdx.x * blockDim.x + threadIdx.x;
  if (e < N_EDGES) atomicAdd(&deg[dst[e]], 1);
}

__global__ __launch_bounds__(1024) void scan_kernel(const int* __restrict__ deg,
                                                    int* __restrict__ offsets) {
  __shared__ int part[1024];
  const int t = threadIdx.x;
  const int base = t * 32;
  int vals[32];
  if (t < 1000) {
#pragma unroll
    for (int j = 0; j < 8; ++j) {
      int4 v = *(const int4*)(deg + base + j * 4);
      vals[j * 4 + 0] = v.x; vals[j * 4 + 1] = v.y;
      vals[j * 4 + 2] = v.z; vals[j * 4 + 3] = v.w;
    }
  } else {
#pragma unroll
    for (int i = 0; i < 32; ++i) vals[i] = 0;
  }
  int local[32];
  int s = 0;
#pragma unroll
  for (int i = 0; i < 32; ++i) { local[i] = s; s += vals[i]; }
  part[t] = s;
  __syncthreads();
  for (int off = 1; off < 1024; off <<= 1) {
    int v = (t >= off) ? part[t - off] : 0;
    __syncthreads();
    part[t] += v;
    __syncthreads();
  }
  int excl = part[t] - s;
  if (t < 1000) {
#pragma unroll
    for (int i = 0; i < 32; ++i) offsets[base + i] = excl + local[i];
  }
  if (t == 1023) offsets[N_NODES] = part[1023];
}

__global__ void scatter_kernel(const int* __restrict__ src, const int* __restrict__ dst,
                               const int* __restrict__ offsets, int* __restrict__ cursor,
                               int* __restrict__ srcSorted) {
  int e = blockIdx.x * blockDim.x + threadIdx.x;
  if (e < N_EDGES) {
    int d = dst[e];
    int pos = offsets[d] + atomicAdd(&cursor[d], 1);
    srcSorted[pos] = src[e];
  }
}

// ---------------- fused aggregate + Xp: Z stays in registers ----------------
// 512 blocks = 32 graphs x 16 chunks (8x63 + 8x62 nodes). Per node: edge-gather mean,
// softmax (threads 0..7), write Ss, accumulate xc[c] += Ss[c]*Z[t]. Atomic flush to Xp.
__global__ __launch_bounds__(256) void aggxp_kernel(
    const _Float16* __restrict__ C,
    const int* __restrict__ offsets, const int* __restrict__ srcSorted,
    const float* __restrict__ bl1, const float* __restrict__ bla,
    float* __restrict__ Ss, float* __restrict__ Xp)
{
  const int blk = blockIdx.x;
  const int g = blk >> 4, ch = blk & 15;
  const int n0 = g * NPG + (ch < 8 ? ch * 63 : 504 + (ch - 8) * 62);
  const int nn = (ch < 8) ? 63 : 62;
  const int t = threadIdx.x;
  __shared__ float sS[8];
  __shared__ float sSm[8];
  float xc[8] = {0.f, 0.f, 0.f, 0.f, 0.f, 0.f, 0.f, 0.f};
  const float blv = bl1[t];
  const float blav = (t < 8) ? bla[t] : 0.f;

  for (int i = 0; i < nn; ++i) {
    const int node = n0 + i;
    const int b = offsets[node], e = offsets[node + 1];
    float accP = 0.f;
    for (int p = b; p < e; ++p)
      accP += (float)C[(size_t)srcSorted[p] * NW + t];
    const float inv = (e > b) ? 1.f / (float)(e - b) : 0.f;
    const float z = fmaxf(accP * inv + blv + (float)C[(size_t)node * NW + 256 + t], 0.f);

    if (t < 8) {
      float a = 0.f;
      for (int p = b; p < e; ++p)
        a += (float)C[(size_t)srcSorted[p] * NW + 512 + t];
      sS[t] = a * inv + blav + (float)C[(size_t)node * NW + 520 + t];
    }
    __syncthreads();
    if (t < 8) {
      float m = sS[0];
#pragma unroll
      for (int c = 1; c < 8; ++c) m = fmaxf(m, sS[c]);
      float denom = 0.f;
#pragma unroll
      for (int c = 0; c < 8; ++c) denom += expf(sS[c] - m);
      const float v = expf(sS[t] - m) / denom;
      sSm[t] = v;
      Ss[(size_t)node * 8 + t] = v;
    }
    __syncthreads();
#pragma unroll
    for (int c = 0; c < 8; ++c) xc[c] = fmaf(sSm[c], z, xc[c]);
  }
#pragma unroll
  for (int c = 0; c < 8; ++c)
    atomicAdd(&Xp[((size_t)g * 8 + c) * 256 + t], xc[c]);
}

// ---------------- Ap[g,i,j] += sum_{n in chunk} AggS[n][i] * Ss[n][j] ----------------
__global__ __launch_bounds__(256) void ap_kernel(
    const float* __restrict__ Ss,
    const int* __restrict__ offsets, const int* __restrict__ srcSorted,
    float* __restrict__ Ap)
{
  const int g = blockIdx.x >> 3;
  const int chunk = blockIdx.x & 7;
  const int n0 = g * NPG + chunk * 125;
  const int t = threadIdx.x;
  __shared__ float lSs[125][8];
  __shared__ float lAg[125][8];
  __shared__ float apTmp[4][64];

  if (t < 125) {
    const int node = n0 + t;
    float4 s0 = *(const float4*)&Ss[(size_t)node * 8];
    float4 s1 = *(const float4*)&Ss[(size_t)node * 8 + 4];
    lSs[t][0] = s0.x; lSs[t][1] = s0.y; lSs[t][2] = s0.z; lSs[t][3] = s0.w;
    lSs[t][4] = s1.x; lSs[t][5] = s1.y; lSs[t][6] = s1.z; lSs[t][7] = s1.w;
    float a[8] = {0.f, 0.f, 0.f, 0.f, 0.f, 0.f, 0.f, 0.f};
    const int b = offsets[node], e = offsets[node + 1];
    for (int p = b; p < e; ++p) {
      const int s = srcSorted[p];
      float4 v0 = *(const float4*)&Ss[(size_t)s * 8];
      float4 v1 = *(const float4*)&Ss[(size_t)s * 8 + 4];
      a[0] += v0.x; a[1] += v0.y; a[2] += v0.z; a[3] += v0.w;
      a[4] += v1.x; a[5] += v1.y; a[6] += v1.z; a[7] += v1.w;
    }
#pragma unroll
    for (int c = 0; c < 8; ++c) lAg[t][c] = a[c];
  }
  __syncthreads();
  {
    const int sl = t >> 6, i = (t >> 3) & 7, j = t & 7;
    float acc = 0.f;
    for (int n = sl; n < 125; n += 4) acc += lAg[n][i] * lSs[n][j];
    apTmp[sl][((i << 3) | j)] = acc;
  }
  __syncthreads();
  if (t < 64) atomicAdd(&Ap[g * 64 + t], apTmp[0][t] + apTmp[1][t] + apTmp[2][t] + apTmp[3][t]);
}

// ---------------- final: mask/deg -> agg -> Zp -> classifier -> out[g] ----------------
__global__ __launch_bounds__(1024) void final_kernel(
    const float* __restrict__ Xp, const float* __restrict__ Ap,
    const float* __restrict__ Wl2, const float* __restrict__ bl2,
    const float* __restrict__ Wr2, const float* __restrict__ Wc1,
    const float* __restrict__ bc1, const float* __restrict__ Wc2,
    const float* __restrict__ bc2, float* __restrict__ out)
{
  const int g = blockIdx.x;
  const int t = threadIdx.x;
  const int c = t & 255, q = t >> 8;
  __shared__ float lAp[64];
  __shared__ float lXp[8][256];
  __shared__ float lAgg[8][256];
  __shared__ float lG[2048];
  __shared__ float part[4][256];
  __shared__ float red[256];
  if (t < 64) lAp[t] = Ap[g * 64 + t];
  lXp[q][c]     = Xp[((size_t)g * 8 + q) * 256 + c];
  lXp[q + 4][c] = Xp[((size_t)g * 8 + q + 4) * 256 + c];
  __syncthreads();
#pragma unroll
  for (int jj = 0; jj < 2; ++jj) {
    int j = q + jj * 4;
    float d = 0.f, s = 0.f;
#pragma unroll
    for (int i = 0; i < 8; ++i) {
      bool m = (lAp[i * 8 + j] != 0.f);
      d += m ? 1.f : 0.f;
      s += m ? lXp[i][c] : 0.f;
    }
    lAgg[j][c] = (d > 0.f) ? s / fmaxf(d, 1.f) : 0.f;
  }
  __syncthreads();
#pragma unroll
  for (int jj = 0; jj < 2; ++jj) {
    int j = q + jj * 4;
    float az = bl2[c];
#pragma unroll 4
    for (int k = 0; k < 256; ++k) {
      az += lAgg[j][k] * Wl2[(size_t)k * 256 + c] + lXp[j][k] * Wr2[(size_t)k * 256 + c];
    }
    lG[j * 256 + c] = fmaxf(az, 0.f);
  }
  __syncthreads();
  float a = 0.f;
  const int kb = q * 512;
#pragma unroll 4
  for (int k = kb; k < kb + 512; ++k) a = fmaf(lG[k], Wc1[(size_t)k * 256 + c], a);
  part[q][c] = a;
  __syncthreads();
  if (t < 256) {
    float s = bc1[t] + part[0][t] + part[1][t] + part[2][t] + part[3][t];
    red[t] = fmaxf(s, 0.f) * Wc2[t];
  }
  __syncthreads();
  for (int off = 128; off > 0; off >>= 1) {
    if (t < off) red[t] += red[t + off];
    __syncthreads();
  }
  if (t == 0) out[g] = red[0] + bc2[0];
}

extern "C" void kernel_launch(void* const* d_in, const int* in_sizes, int n_in,
                              void* d_out, int out_size, void* d_ws, size_t ws_size,
                              hipStream_t stream) {
  const float* x   = (const float*)d_in[0];
  const int*   ei  = (const int*)d_in[1];
  const float* Wl1 = (const float*)d_in[3];
  const float* bl1 = (const float*)d_in[4];
  const float* Wr1 = (const float*)d_in[5];
  const float* Wla = (const float*)d_in[6];
  const float* bla = (const float*)d_in[7];
  const float* Wra = (const float*)d_in[8];
  const float* Wl2 = (const float*)d_in[9];
  const float* bl2 = (const float*)d_in[10];
  const float* Wr2 = (const float*)d_in[11];
  const float* Wc1 = (const float*)d_in[12];
  const float* bc1 = (const float*)d_in[13];
  const float* Wc2 = (const float*)d_in[14];
  const float* bc2 = (const float*)d_in[15];
  float* out = (float*)d_out;

  // workspace layout (~169 MB)
  _Float16* C    = (_Float16*)d_ws;                 // 32000*528
  _Float16* WsT2 = C + (size_t)32000 * NW;          // 540672
  _Float16* XH   = WsT2 + 540672;                   // 32000*1024
  _Float16* XL   = XH + (size_t)32000 * 1024;       // 32000*1024
  float* Ss   = (float*)(XL + (size_t)32000 * 1024); // 32000*8
  float* Xp   = Ss + 256000;                        // 32*8*256
  float* Ap   = Xp + 65536;                         // 32*64
  int* deg     = (int*)(Ap + 2048);                 // 32000
  int* cursor  = deg + 32000;                       // 32000
  int* offsets = cursor + 32000;                    // 32001
  int* srcS    = offsets + 32001;                   // 256000
  unsigned* zbuf = (unsigned*)Xp;                   // Xp+Ap+deg+cursor = 131584 words

  const int* src = ei;
  const int* dst = ei + N_EDGES;

  prep_kernel<<<dim3(3, 128), 256, 0, stream>>>(Wl1, Wr1, Wla, Wra, WsT2, zbuf);
  xsplit<<<16000, 256, 0, stream>>>(x, XH, XL);
  count_deg<<<1000, 256, 0, stream>>>(dst, deg);
  scan_kernel<<<1, 1024, 0, stream>>>(deg, offsets);
  scatter_kernel<<<1000, 256, 0, stream>>>(src, dst, offsets, cursor, srcS);
  gemm_mfma<<<1250, 256, 0, stream>>>(XH, XL, WsT2, C);
  aggxp_kernel<<<512, 256, 0, stream>>>(C, offsets, srcS, bl1, bla, Ss, Xp);
  ap_kernel<<<256, 256, 0, stream>>>(Ss, offsets, srcS, Ap);
  final_kernel<<<32, 1024, 0, stream>>>(Xp, Ap, Wl2, bl2, Wr2, Wc1, bc1, Wc2, bc2, out);
}

// Round 6
// 390.260 us; speedup vs baseline: 1.5996x; 1.5996x over previous
//
#include <hip/hip_runtime.h>
#include <hip/hip_bf16.h>
#include <math.h>

#define N_NODES 32000
#define NUM_GRAPHS 32
#define NPG 1000
#define N_EDGES 256000
#define IN_DIM 1024
#define HID 256
#define NW 528    // C width: 256 (Wl1) + 256 (Wr1) + 8 (Wla) + 8 (Wra)
#define KBH 1040  // LDS halves-stride per kb-block: 128*8 + 16 pad (2080 B = 2x1024B wave segs + 32B)

typedef _Float16 half8 __attribute__((ext_vector_type(8)));
typedef float f32x4 __attribute__((ext_vector_type(4)));

__device__ __forceinline__ void gload16(const void* g, void* l) {
  __builtin_amdgcn_global_load_lds((const __attribute__((address_space(1))) void*)g,
                                   (__attribute__((address_space(3))) void*)l, 16, 0, 0);
}

// ---------------- prep: zero scratch counters + build tiled fp16 weight buffer ----------------
__global__ __launch_bounds__(256) void prep_kernel(
    const float* __restrict__ Wl1, const float* __restrict__ Wr1,
    const float* __restrict__ Wla, const float* __restrict__ Wra,
    _Float16* __restrict__ WsT2, unsigned* __restrict__ zbuf)
{
  const int t = threadIdx.x;
  const int flat = blockIdx.y * 3 + blockIdx.x;   // 0..383
  for (int i = flat * 256 + t; i < 131584; i += 384 * 256) zbuf[i] = 0u;

  const int kslot = blockIdx.y;        // 0..127 -> k0 = kslot*8
  const int n = blockIdx.x * 256 + t;
  if (n >= NW) return;
  const int k0 = kslot * 8;
  half8 o;
#pragma unroll
  for (int i = 0; i < 8; ++i) {
    const int k = k0 + i;
    float v;
    if (n < 256)      v = Wl1[(size_t)k * 256 + n];
    else if (n < 512) v = Wr1[(size_t)k * 256 + n - 256];
    else if (n < 520) v = Wla[(size_t)k * 8 + n - 512];
    else              v = Wra[(size_t)k * 8 + n - 520];
    o[i] = (_Float16)v;
  }
  const int K = kslot >> 2, kb = kslot & 3;
  size_t off;
  if (n < 512) off = (size_t)K * 16896 + (size_t)(n >> 7) * 4096 + kb * 1024 + (n & 127) * 8;
  else         off = (size_t)K * 16896 + 16384 + kb * 128 + (n - 512) * 8;
  *(half8*)&WsT2[off] = o;
}

// ---------------- xsplit: XH = fp16(x), XL = fp16(x - XH) ----------------
__global__ __launch_bounds__(256) void xsplit(
    const float* __restrict__ x, _Float16* __restrict__ XH, _Float16* __restrict__ XL)
{
  const size_t i = ((size_t)blockIdx.x * 256 + threadIdx.x) * 8;
  float4 a = *(const float4*)(x + i);
  float4 b = *(const float4*)(x + i + 4);
  float v[8] = {a.x, a.y, a.z, a.w, b.x, b.y, b.z, b.w};
  half8 h, l;
#pragma unroll
  for (int j = 0; j < 8; ++j) {
    _Float16 hv = (_Float16)v[j];
    h[j] = hv;
    l[j] = (_Float16)(v[j] - (float)hv);
  }
  *(half8*)&XH[i] = h;
  *(half8*)&XL[i] = l;
}

// ---------------- MFMA GEMM: C[32000,528](fp16) = x @ [Wl1|Wr1|Wla|Wra], split-fp16 ----------------
// Pure global_load_lds staging (AH, AL, B). 1250 blocks = 250 m-panels x 5 nb.
__global__ __launch_bounds__(256) void gemm_mfma(
    const _Float16* __restrict__ XH, const _Float16* __restrict__ XL,
    const _Float16* __restrict__ WsT2, _Float16* __restrict__ C)
{
  const int orig = blockIdx.x;
  const int xcd = orig & 7, idx = orig >> 3;
  // bijective XCD swizzle, nwg=1250: q=156, r=2
  const int g = (xcd < 2 ? xcd * 157 : 314 + (xcd - 2) * 156) + idx;
  const int pm = g / 5, nb = g % 5;
  const int m0 = pm * 128;

  __shared__ _Float16 AH[4 * KBH];
  __shared__ _Float16 AL[4 * KBH];
  __shared__ _Float16 Bs[4 * KBH];

  const int tid = threadIdx.x;
  const int w = tid >> 6, l = tid & 63;
  const int wr = w >> 1, wc = w & 1;
  const int r16 = l & 15, kb4 = l >> 4;

  const int q0 = tid & 127, kb0 = tid >> 7;
  const int kb1 = kb0 + 2;
  const int lpA0 = kb0 * KBH + q0 * 8;
  const int lpA1 = kb1 * KBH + q0 * 8;
  const _Float16* gah0 = XH + (size_t)(m0 + q0) * IN_DIM + kb0 * 8;
  const _Float16* gah1 = XH + (size_t)(m0 + q0) * IN_DIM + kb1 * 8;
  const _Float16* gal0 = XL + (size_t)(m0 + q0) * IN_DIM + kb0 * 8;
  const _Float16* gal1 = XL + (size_t)(m0 + q0) * IN_DIM + kb1 * 8;

  if (nb < 4) {
    const int lpB0 = (tid >> 7) * KBH + (tid & 127) * 8;
    const int lpB1 = ((tid + 256) >> 7) * KBH + ((tid + 256) & 127) * 8;
    const _Float16* gb0 = WsT2 + nb * 4096 + tid * 8;
    const _Float16* gb1 = WsT2 + nb * 4096 + (tid + 256) * 8;

    f32x4 acc[4][4] = {};
    for (int ks = 0; ks < 32; ++ks) {
      __syncthreads();
      gload16(gah0 + ks * 32, &AH[lpA0]);
      gload16(gah1 + ks * 32, &AH[lpA1]);
      gload16(gal0 + ks * 32, &AL[lpA0]);
      gload16(gal1 + ks * 32, &AL[lpA1]);
      gload16(gb0 + (size_t)ks * 16896, &Bs[lpB0]);
      gload16(gb1 + (size_t)ks * 16896, &Bs[lpB1]);
      __syncthreads();

      half8 bf[4];
#pragma unroll
      for (int n = 0; n < 4; ++n)
        bf[n] = *(half8*)&Bs[kb4 * KBH + (wc * 64 + n * 16 + r16) * 8];
#pragma unroll
      for (int m = 0; m < 4; ++m) {
        half8 ah = *(half8*)&AH[kb4 * KBH + (wr * 64 + m * 16 + r16) * 8];
        half8 al = *(half8*)&AL[kb4 * KBH + (wr * 64 + m * 16 + r16) * 8];
#pragma unroll
        for (int n = 0; n < 4; ++n) {
          acc[m][n] = __builtin_amdgcn_mfma_f32_16x16x32_f16(ah, bf[n], acc[m][n], 0, 0, 0);
          acc[m][n] = __builtin_amdgcn_mfma_f32_16x16x32_f16(al, bf[n], acc[m][n], 0, 0, 0);
        }
      }
    }
    const int crow0 = m0 + wr * 64 + ((l >> 4) << 2);
    const int ccol0 = nb * 128 + wc * 64 + r16;
#pragma unroll
    for (int m = 0; m < 4; ++m)
#pragma unroll
      for (int n = 0; n < 4; ++n)
#pragma unroll
        for (int r = 0; r < 4; ++r)
          C[(size_t)(crow0 + m * 16 + r) * NW + ccol0 + n * 16] = (_Float16)acc[m][n][r];
  } else {
    const _Float16* gb0 = WsT2 + 16384 + tid * 8;

    f32x4 acc2[2] = {};
    for (int ks = 0; ks < 32; ++ks) {
      __syncthreads();
      gload16(gah0 + ks * 32, &AH[lpA0]);
      gload16(gah1 + ks * 32, &AH[lpA1]);
      gload16(gal0 + ks * 32, &AL[lpA0]);
      gload16(gal1 + ks * 32, &AL[lpA1]);
      if (tid < 64) gload16(gb0 + (size_t)ks * 16896, &Bs[tid * 8]);
      __syncthreads();

      half8 bf = *(half8*)&Bs[(kb4 * 16 + r16) * 8];
#pragma unroll
      for (int m = 0; m < 2; ++m) {
        half8 ah = *(half8*)&AH[kb4 * KBH + (w * 32 + m * 16 + r16) * 8];
        half8 al = *(half8*)&AL[kb4 * KBH + (w * 32 + m * 16 + r16) * 8];
        acc2[m] = __builtin_amdgcn_mfma_f32_16x16x32_f16(ah, bf, acc2[m], 0, 0, 0);
        acc2[m] = __builtin_amdgcn_mfma_f32_16x16x32_f16(al, bf, acc2[m], 0, 0, 0);
      }
    }
    const int crow0 = m0 + w * 32 + ((l >> 4) << 2);
    const int ccol0 = 512 + r16;
#pragma unroll
    for (int m = 0; m < 2; ++m)
#pragma unroll
      for (int r = 0; r < 4; ++r)
        C[(size_t)(crow0 + m * 16 + r) * NW + ccol0] = (_Float16)acc2[m][r];
  }
}

// ---------------- CSR build ----------------
__global__ void count_deg(const int* __restrict__ dst, int* __restrict__ deg) {
  int e = blockIdx.x * blockDim.x + threadIdx.x;
  if (e < N_EDGES) atomicAdd(&deg[dst[e]], 1);
}

__global__ __launch_bounds__(1024) void scan_kernel(const int* __restrict__ deg,
                                                    int* __restrict__ offsets) {
  __shared__ int part[1024];
  const int t = threadIdx.x;
  const int base = t * 32;
  int vals[32];
  if (t < 1000) {
#pragma unroll
    for (int j = 0; j < 8; ++j) {
      int4 v = *(const int4*)(deg + base + j * 4);
      vals[j * 4 + 0] = v.x; vals[j * 4 + 1] = v.y;
      vals[j * 4 + 2] = v.z; vals[j * 4 + 3] = v.w;
    }
  } else {
#pragma unroll
    for (int i = 0; i < 32; ++i) vals[i] = 0;
  }
  int local[32];
  int s = 0;
#pragma unroll
  for (int i = 0; i < 32; ++i) { local[i] = s; s += vals[i]; }
  part[t] = s;
  __syncthreads();
  for (int off = 1; off < 1024; off <<= 1) {
    int v = (t >= off) ? part[t - off] : 0;
    __syncthreads();
    part[t] += v;
    __syncthreads();
  }
  int excl = part[t] - s;
  if (t < 1000) {
#pragma unroll
    for (int i = 0; i < 32; ++i) offsets[base + i] = excl + local[i];
  }
  if (t == 1023) offsets[N_NODES] = part[1023];
}

__global__ void scatter_kernel(const int* __restrict__ src, const int* __restrict__ dst,
                               const int* __restrict__ offsets, int* __restrict__ cursor,
                               int* __restrict__ srcSorted) {
  int e = blockIdx.x * blockDim.x + threadIdx.x;
  if (e < N_EDGES) {
    int d = dst[e];
    int pos = offsets[d] + atomicAdd(&cursor[d], 1);
    srcSorted[pos] = src[e];
  }
}

// ---------------- per-node aggregation: Z (fp16) + Ss from C ----------------
__global__ __launch_bounds__(256) void aggregate_node(
    const _Float16* __restrict__ C,
    const int* __restrict__ offsets, const int* __restrict__ srcSorted,
    const float* __restrict__ bl1, const float* __restrict__ bla,
    _Float16* __restrict__ Zh, float* __restrict__ Ss)
{
  const int bid = blockIdx.x;
  const int node = (bid & 7) * 4000 + (bid >> 3);   // graphs pinned to XCDs
  const int t = threadIdx.x;
  const int b = offsets[node], e = offsets[node + 1];
  const int cnt = e - b;
  float accP = 0.f;
  for (int p = b; p < e; ++p) {
    int s = srcSorted[p];
    accP += (float)C[(size_t)s * NW + t];
  }
  const float inv = (cnt > 0) ? 1.f / (float)cnt : 0.f;
  float z = accP * inv + bl1[t] + (float)C[(size_t)node * NW + 256 + t];
  Zh[(size_t)node * 256 + t] = (_Float16)fmaxf(z, 0.f);

  __shared__ float sS[8];
  if (t < 8) {
    float a = 0.f;
    for (int p = b; p < e; ++p) a += (float)C[(size_t)srcSorted[p] * NW + 512 + t];
    sS[t] = a * inv + bla[t] + (float)C[(size_t)node * NW + 520 + t];
  }
  __syncthreads();
  if (t < 8) {
    float m = sS[0];
#pragma unroll
    for (int c = 1; c < 8; ++c) m = fmaxf(m, sS[c]);
    float denom = 0.f;
#pragma unroll
    for (int c = 0; c < 8; ++c) denom += expf(sS[c] - m);
    Ss[(size_t)node * 8 + t] = expf(sS[t] - m) / denom;
  }
}

// ---------------- pool: per 125-node chunk: AggS (LDS) -> Ap partial + Xp partial ----------------
__global__ __launch_bounds__(256) void pool_kernel(
    const float* __restrict__ Ss, const _Float16* __restrict__ Zh,
    const int* __restrict__ offsets, const int* __restrict__ srcSorted,
    float* __restrict__ Xp, float* __restrict__ Ap)
{
  const int g = blockIdx.x >> 3;
  const int chunk = blockIdx.x & 7;
  const int n0 = g * NPG + chunk * 125;
  const int t = threadIdx.x;
  __shared__ float lSs[125][8];
  __shared__ float lAg[125][8];
  __shared__ float apTmp[4][64];

  if (t < 125) {
    const int node = n0 + t;
    float4 s0 = *(const float4*)&Ss[(size_t)node * 8];
    float4 s1 = *(const float4*)&Ss[(size_t)node * 8 + 4];
    lSs[t][0] = s0.x; lSs[t][1] = s0.y; lSs[t][2] = s0.z; lSs[t][3] = s0.w;
    lSs[t][4] = s1.x; lSs[t][5] = s1.y; lSs[t][6] = s1.z; lSs[t][7] = s1.w;
    float a[8] = {0.f, 0.f, 0.f, 0.f, 0.f, 0.f, 0.f, 0.f};
    const int b = offsets[node], e = offsets[node + 1];
    for (int p = b; p < e; ++p) {
      const int s = srcSorted[p];
      float4 v0 = *(const float4*)&Ss[(size_t)s * 8];
      float4 v1 = *(const float4*)&Ss[(size_t)s * 8 + 4];
      a[0] += v0.x; a[1] += v0.y; a[2] += v0.z; a[3] += v0.w;
      a[4] += v1.x; a[5] += v1.y; a[6] += v1.z; a[7] += v1.w;
    }
#pragma unroll
    for (int c = 0; c < 8; ++c) lAg[t][c] = a[c];
  }
  __syncthreads();
  {
    const int sl = t >> 6, i = (t >> 3) & 7, j = t & 7;
    float acc = 0.f;
    for (int n = sl; n < 125; n += 4) acc += lAg[n][i] * lSs[n][j];
    apTmp[sl][((i << 3) | j)] = acc;
  }
  __syncthreads();
  if (t < 64) atomicAdd(&Ap[g * 64 + t], apTmp[0][t] + apTmp[1][t] + apTmp[2][t] + apTmp[3][t]);
  // Xp partial
  float xc[8] = {0.f, 0.f, 0.f, 0.f, 0.f, 0.f, 0.f, 0.f};
  for (int n = 0; n < 125; ++n) {
    float zv = (float)Zh[(size_t)(n0 + n) * 256 + t];
#pragma unroll
    for (int c = 0; c < 8; ++c) xc[c] = fmaf(lSs[n][c], zv, xc[c]);
  }
#pragma unroll
  for (int c = 0; c < 8; ++c)
    atomicAdd(&Xp[((size_t)g * 8 + c) * 256 + t], xc[c]);
}

// ---------------- final: mask/deg -> agg -> Zp -> classifier -> out[g] ----------------
__global__ __launch_bounds__(1024) void final_kernel(
    const float* __restrict__ Xp, const float* __restrict__ Ap,
    const float* __restrict__ Wl2, const float* __restrict__ bl2,
    const float* __restrict__ Wr2, const float* __restrict__ Wc1,
    const float* __restrict__ bc1, const float* __restrict__ Wc2,
    const float* __restrict__ bc2, float* __restrict__ out)
{
  const int g = blockIdx.x;
  const int t = threadIdx.x;
  const int c = t & 255, q = t >> 8;
  __shared__ float lAp[64];
  __shared__ float lXp[8][256];
  __shared__ float lAgg[8][256];
  __shared__ float lG[2048];
  __shared__ float part[4][256];
  __shared__ float red[256];
  if (t < 64) lAp[t] = Ap[g * 64 + t];
  lXp[q][c]     = Xp[((size_t)g * 8 + q) * 256 + c];
  lXp[q + 4][c] = Xp[((size_t)g * 8 + q + 4) * 256 + c];
  __syncthreads();
#pragma unroll
  for (int jj = 0; jj < 2; ++jj) {
    int j = q + jj * 4;
    float d = 0.f, s = 0.f;
#pragma unroll
    for (int i = 0; i < 8; ++i) {
      bool m = (lAp[i * 8 + j] != 0.f);
      d += m ? 1.f : 0.f;
      s += m ? lXp[i][c] : 0.f;
    }
    lAgg[j][c] = (d > 0.f) ? s / fmaxf(d, 1.f) : 0.f;
  }
  __syncthreads();
#pragma unroll
  for (int jj = 0; jj < 2; ++jj) {
    int j = q + jj * 4;
    float az = bl2[c];
#pragma unroll 4
    for (int k = 0; k < 256; ++k) {
      az += lAgg[j][k] * Wl2[(size_t)k * 256 + c] + lXp[j][k] * Wr2[(size_t)k * 256 + c];
    }
    lG[j * 256 + c] = fmaxf(az, 0.f);
  }
  __syncthreads();
  float a = 0.f;
  const int kb = q * 512;
#pragma unroll 4
  for (int k = kb; k < kb + 512; ++k) a = fmaf(lG[k], Wc1[(size_t)k * 256 + c], a);
  part[q][c] = a;
  __syncthreads();
  if (t < 256) {
    float s = bc1[t] + part[0][t] + part[1][t] + part[2][t] + part[3][t];
    red[t] = fmaxf(s, 0.f) * Wc2[t];
  }
  __syncthreads();
  for (int off = 128; off > 0; off >>= 1) {
    if (t < off) red[t] += red[t + off];
    __syncthreads();
  }
  if (t == 0) out[g] = red[0] + bc2[0];
}

extern "C" void kernel_launch(void* const* d_in, const int* in_sizes, int n_in,
                              void* d_out, int out_size, void* d_ws, size_t ws_size,
                              hipStream_t stream) {
  const float* x   = (const float*)d_in[0];
  const int*   ei  = (const int*)d_in[1];
  const float* Wl1 = (const float*)d_in[3];
  const float* bl1 = (const float*)d_in[4];
  const float* Wr1 = (const float*)d_in[5];
  const float* Wla = (const float*)d_in[6];
  const float* bla = (const float*)d_in[7];
  const float* Wra = (const float*)d_in[8];
  const float* Wl2 = (const float*)d_in[9];
  const float* bl2 = (const float*)d_in[10];
  const float* Wr2 = (const float*)d_in[11];
  const float* Wc1 = (const float*)d_in[12];
  const float* bc1 = (const float*)d_in[13];
  const float* Wc2 = (const float*)d_in[14];
  const float* bc2 = (const float*)d_in[15];
  float* out = (float*)d_out;

  // workspace layout (~186 MB)
  _Float16* C    = (_Float16*)d_ws;                  // 32000*528
  _Float16* WsT2 = C + (size_t)32000 * NW;           // 540672
  _Float16* XH   = WsT2 + 540672;                    // 32000*1024
  _Float16* XL   = XH + (size_t)32000 * 1024;        // 32000*1024
  _Float16* Zh   = XL + (size_t)32000 * 1024;        // 32000*256
  float* Ss   = (float*)(Zh + (size_t)32000 * 256);  // 32000*8
  float* Xp   = Ss + 256000;                         // 32*8*256
  float* Ap   = Xp + 65536;                          // 32*64
  int* deg     = (int*)(Ap + 2048);                  // 32000
  int* cursor  = deg + 32000;                        // 32000
  int* offsets = cursor + 32000;                     // 32001
  int* srcS    = offsets + 32001;                    // 256000
  unsigned* zbuf = (unsigned*)Xp;                    // Xp+Ap+deg+cursor = 131584 words

  const int* src = ei;
  const int* dst = ei + N_EDGES;

  prep_kernel<<<dim3(3, 128), 256, 0, stream>>>(Wl1, Wr1, Wla, Wra, WsT2, zbuf);
  xsplit<<<16000, 256, 0, stream>>>(x, XH, XL);
  count_deg<<<1000, 256, 0, stream>>>(dst, deg);
  scan_kernel<<<1, 1024, 0, stream>>>(deg, offsets);
  scatter_kernel<<<1000, 256, 0, stream>>>(src, dst, offsets, cursor, srcS);
  gemm_mfma<<<1250, 256, 0, stream>>>(XH, XL, WsT2, C);
  aggregate_node<<<32000, 256, 0, stream>>>(C, offsets, srcS, bl1, bla, Zh, Ss);
  pool_kernel<<<256, 256, 0, stream>>>(Ss, Zh, offsets, srcS, Xp, Ap);
  final_kernel<<<32, 1024, 0, stream>>>(Xp, Ap, Wl2, bl2, Wr2, Wc1, bc1, Wc2, bc2, out);
}

// Round 7
// 365.432 us; speedup vs baseline: 1.7083x; 1.0679x over previous
//
#include <hip/hip_runtime.h>
#include <hip/hip_bf16.h>
#include <math.h>

#define N_NODES 32000
#define NUM_GRAPHS 32
#define NPG 1000
#define N_EDGES 256000
#define IN_DIM 1024
#define HID 256
#define NW 528    // C width: 256 (Wl1) + 256 (Wr1) + 8 (Wla) + 8 (Wra)
#define KBH 1040  // LDS halves-stride per kb-block: 128*8 + 16 pad

typedef _Float16 half8 __attribute__((ext_vector_type(8)));
typedef _Float16 half4 __attribute__((ext_vector_type(4)));
typedef float f32x4 __attribute__((ext_vector_type(4)));

__device__ __forceinline__ void gload16(const void* g, void* l) {
  __builtin_amdgcn_global_load_lds((const __attribute__((address_space(1))) void*)g,
                                   (__attribute__((address_space(3))) void*)l, 16, 0, 0);
}

// ---------------- prep: zero scratch counters + build tiled fp16 weight buffer ----------------
__global__ __launch_bounds__(256) void prep_kernel(
    const float* __restrict__ Wl1, const float* __restrict__ Wr1,
    const float* __restrict__ Wla, const float* __restrict__ Wra,
    _Float16* __restrict__ WsT2, unsigned* __restrict__ zbuf)
{
  const int t = threadIdx.x;
  const int flat = blockIdx.y * 3 + blockIdx.x;   // 0..383
  for (int i = flat * 256 + t; i < 131584; i += 384 * 256) zbuf[i] = 0u;

  const int kslot = blockIdx.y;        // 0..127 -> k0 = kslot*8
  const int n = blockIdx.x * 256 + t;
  if (n >= NW) return;
  const int k0 = kslot * 8;
  half8 o;
#pragma unroll
  for (int i = 0; i < 8; ++i) {
    const int k = k0 + i;
    float v;
    if (n < 256)      v = Wl1[(size_t)k * 256 + n];
    else if (n < 512) v = Wr1[(size_t)k * 256 + n - 256];
    else if (n < 520) v = Wla[(size_t)k * 8 + n - 512];
    else              v = Wra[(size_t)k * 8 + n - 520];
    o[i] = (_Float16)v;
  }
  const int K = kslot >> 2, kb = kslot & 3;
  size_t off;
  if (n < 512) off = (size_t)K * 16896 + (size_t)(n >> 7) * 4096 + kb * 1024 + (n & 127) * 8;
  else         off = (size_t)K * 16896 + 16384 + kb * 128 + (n - 512) * 8;
  *(half8*)&WsT2[off] = o;
}

// ---------------- xsplit: XH = fp16(x), XL = fp16(x - XH) ----------------
__global__ __launch_bounds__(256) void xsplit(
    const float* __restrict__ x, _Float16* __restrict__ XH, _Float16* __restrict__ XL)
{
  const size_t i = ((size_t)blockIdx.x * 256 + threadIdx.x) * 8;
  float4 a = *(const float4*)(x + i);
  float4 b = *(const float4*)(x + i + 4);
  float v[8] = {a.x, a.y, a.z, a.w, b.x, b.y, b.z, b.w};
  half8 h, l;
#pragma unroll
  for (int j = 0; j < 8; ++j) {
    _Float16 hv = (_Float16)v[j];
    h[j] = hv;
    l[j] = (_Float16)(v[j] - (float)hv);
  }
  *(half8*)&XH[i] = h;
  *(half8*)&XL[i] = l;
}

// ---------------- MFMA GEMM, 2-phase double-buffered global_load_lds ----------------
// C[32000,528](fp16) = x @ [Wl1|Wr1|Wla|Wra] via split-fp16 (XH+XL).
// Per K-step: stage(next, buf^1) issued BEFORE compute(buf); one barrier per step.
__global__ __launch_bounds__(256) void gemm_mfma(
    const _Float16* __restrict__ XH, const _Float16* __restrict__ XL,
    const _Float16* __restrict__ WsT2, _Float16* __restrict__ C)
{
  const int orig = blockIdx.x;
  const int xcd = orig & 7, idx = orig >> 3;
  // bijective XCD swizzle, nwg=1250: q=156, r=2
  const int g = (xcd < 2 ? xcd * 157 : 314 + (xcd - 2) * 156) + idx;
  const int pm = g / 5, nb = g % 5;
  const int m0 = pm * 128;

  __shared__ _Float16 AH[2][4 * KBH];
  __shared__ _Float16 AL[2][4 * KBH];
  __shared__ _Float16 Bs[2][4 * KBH];

  const int tid = threadIdx.x;
  const int w = tid >> 6, l = tid & 63;
  const int wr = w >> 1, wc = w & 1;
  const int r16 = l & 15, kb4 = l >> 4;

  const int q0 = tid & 127, kb0 = tid >> 7;
  const int kb1 = kb0 + 2;
  const int lpA0 = kb0 * KBH + q0 * 8;
  const int lpA1 = kb1 * KBH + q0 * 8;
  const _Float16* gah0 = XH + (size_t)(m0 + q0) * IN_DIM + kb0 * 8;
  const _Float16* gah1 = XH + (size_t)(m0 + q0) * IN_DIM + kb1 * 8;
  const _Float16* gal0 = XL + (size_t)(m0 + q0) * IN_DIM + kb0 * 8;
  const _Float16* gal1 = XL + (size_t)(m0 + q0) * IN_DIM + kb1 * 8;

  if (nb < 4) {
    const int lpB0 = (tid >> 7) * KBH + (tid & 127) * 8;
    const int lpB1 = ((tid + 256) >> 7) * KBH + ((tid + 256) & 127) * 8;
    const _Float16* gb0 = WsT2 + nb * 4096 + tid * 8;
    const _Float16* gb1 = WsT2 + nb * 4096 + (tid + 256) * 8;

#define STAGE_FULL(KS, BUF)                                   \
    do {                                                      \
      gload16(gah0 + (KS) * 32, &AH[BUF][lpA0]);              \
      gload16(gah1 + (KS) * 32, &AH[BUF][lpA1]);              \
      gload16(gal0 + (KS) * 32, &AL[BUF][lpA0]);              \
      gload16(gal1 + (KS) * 32, &AL[BUF][lpA1]);              \
      gload16(gb0 + (size_t)(KS) * 16896, &Bs[BUF][lpB0]);    \
      gload16(gb1 + (size_t)(KS) * 16896, &Bs[BUF][lpB1]);    \
    } while (0)

    f32x4 acc[4][4] = {};
    STAGE_FULL(0, 0);
    __syncthreads();
    int buf = 0;
    for (int ks = 0; ks < 32; ++ks) {
      if (ks < 31) STAGE_FULL(ks + 1, buf ^ 1);

      half8 bf[4];
#pragma unroll
      for (int n = 0; n < 4; ++n)
        bf[n] = *(half8*)&Bs[buf][kb4 * KBH + (wc * 64 + n * 16 + r16) * 8];
#pragma unroll
      for (int m = 0; m < 4; ++m) {
        half8 ah = *(half8*)&AH[buf][kb4 * KBH + (wr * 64 + m * 16 + r16) * 8];
        half8 al = *(half8*)&AL[buf][kb4 * KBH + (wr * 64 + m * 16 + r16) * 8];
#pragma unroll
        for (int n = 0; n < 4; ++n) {
          acc[m][n] = __builtin_amdgcn_mfma_f32_16x16x32_f16(ah, bf[n], acc[m][n], 0, 0, 0);
          acc[m][n] = __builtin_amdgcn_mfma_f32_16x16x32_f16(al, bf[n], acc[m][n], 0, 0, 0);
        }
      }
      __syncthreads();   // drains staged loads for next step; all waves done with buf
      buf ^= 1;
    }
#undef STAGE_FULL
    const int crow0 = m0 + wr * 64 + ((l >> 4) << 2);
    const int ccol0 = nb * 128 + wc * 64 + r16;
#pragma unroll
    for (int m = 0; m < 4; ++m)
#pragma unroll
      for (int n = 0; n < 4; ++n)
#pragma unroll
        for (int r = 0; r < 4; ++r)
          C[(size_t)(crow0 + m * 16 + r) * NW + ccol0 + n * 16] = (_Float16)acc[m][n][r];
  } else {
    const _Float16* gb0 = WsT2 + 16384 + tid * 8;

#define STAGE_SP(KS, BUF)                                        \
    do {                                                         \
      gload16(gah0 + (KS) * 32, &AH[BUF][lpA0]);                 \
      gload16(gah1 + (KS) * 32, &AH[BUF][lpA1]);                 \
      gload16(gal0 + (KS) * 32, &AL[BUF][lpA0]);                 \
      gload16(gal1 + (KS) * 32, &AL[BUF][lpA1]);                 \
      if (tid < 64) gload16(gb0 + (size_t)(KS) * 16896, &Bs[BUF][tid * 8]); \
    } while (0)

    f32x4 acc2[2] = {};
    STAGE_SP(0, 0);
    __syncthreads();
    int buf = 0;
    for (int ks = 0; ks < 32; ++ks) {
      if (ks < 31) STAGE_SP(ks + 1, buf ^ 1);

      half8 bf = *(half8*)&Bs[buf][(kb4 * 16 + r16) * 8];
#pragma unroll
      for (int m = 0; m < 2; ++m) {
        half8 ah = *(half8*)&AH[buf][kb4 * KBH + (w * 32 + m * 16 + r16) * 8];
        half8 al = *(half8*)&AL[buf][kb4 * KBH + (w * 32 + m * 16 + r16) * 8];
        acc2[m] = __builtin_amdgcn_mfma_f32_16x16x32_f16(ah, bf, acc2[m], 0, 0, 0);
        acc2[m] = __builtin_amdgcn_mfma_f32_16x16x32_f16(al, bf, acc2[m], 0, 0, 0);
      }
      __syncthreads();
      buf ^= 1;
    }
#undef STAGE_SP
    const int crow0 = m0 + w * 32 + ((l >> 4) << 2);
    const int ccol0 = 512 + r16;
#pragma unroll
    for (int m = 0; m < 2; ++m)
#pragma unroll
      for (int r = 0; r < 4; ++r)
        C[(size_t)(crow0 + m * 16 + r) * NW + ccol0] = (_Float16)acc2[m][r];
  }
}

// ---------------- CSR build ----------------
__global__ void count_deg(const int* __restrict__ dst, int* __restrict__ deg) {
  int e = blockIdx.x * blockDim.x + threadIdx.x;
  if (e < N_EDGES) atomicAdd(&deg[dst[e]], 1);
}

__global__ __launch_bounds__(1024) void scan_kernel(const int* __restrict__ deg,
                                                    int* __restrict__ offsets) {
  __shared__ int part[1024];
  const int t = threadIdx.x;
  const int base = t * 32;
  int vals[32];
  if (t < 1000) {
#pragma unroll
    for (int j = 0; j < 8; ++j) {
      int4 v = *(const int4*)(deg + base + j * 4);
      vals[j * 4 + 0] = v.x; vals[j * 4 + 1] = v.y;
      vals[j * 4 + 2] = v.z; vals[j * 4 + 3] = v.w;
    }
  } else {
#pragma unroll
    for (int i = 0; i < 32; ++i) vals[i] = 0;
  }
  int local[32];
  int s = 0;
#pragma unroll
  for (int i = 0; i < 32; ++i) { local[i] = s; s += vals[i]; }
  part[t] = s;
  __syncthreads();
  for (int off = 1; off < 1024; off <<= 1) {
    int v = (t >= off) ? part[t - off] : 0;
    __syncthreads();
    part[t] += v;
    __syncthreads();
  }
  int excl = part[t] - s;
  if (t < 1000) {
#pragma unroll
    for (int i = 0; i < 32; ++i) offsets[base + i] = excl + local[i];
  }
  if (t == 1023) offsets[N_NODES] = part[1023];
}

__global__ void scatter_kernel(const int* __restrict__ src, const int* __restrict__ dst,
                               const int* __restrict__ offsets, int* __restrict__ cursor,
                               int* __restrict__ srcSorted) {
  int e = blockIdx.x * blockDim.x + threadIdx.x;
  if (e < N_EDGES) {
    int d = dst[e];
    int pos = offsets[d] + atomicAdd(&cursor[d], 1);
    srcSorted[pos] = src[e];
  }
}

// ---------------- per-node aggregation: wave-per-node, vectorized gathers ----------------
// Wave lane covers channels 4l..4l+3 (half4 = 8B/lane, 512B/wave per neighbor row).
// Softmax over lanes 0..7 via shfl_xor. 8000 blocks x 4 waves = 32000 nodes.
__global__ __launch_bounds__(256) void aggregate_node(
    const _Float16* __restrict__ C,
    const int* __restrict__ offsets, const int* __restrict__ srcSorted,
    const float* __restrict__ bl1, const float* __restrict__ bla,
    _Float16* __restrict__ Zh, float* __restrict__ Ss)
{
  const int bid = blockIdx.x;
  const int wv = threadIdx.x >> 6, lane = threadIdx.x & 63;
  const int node = (bid & 7) * 4000 + (bid >> 3) * 4 + wv;  // graphs pinned to XCDs
  const int b = offsets[node], e = offsets[node + 1];
  const int cnt = e - b;
  const float4 blv = *(const float4*)(bl1 + 4 * lane);
  float a0 = 0.f, a1 = 0.f, a2 = 0.f, a3 = 0.f, sp = 0.f;
  int p = b;
  int sNext = (p < e) ? srcSorted[p] : 0;
  while (p < e) {
    const int s = sNext;
    ++p;
    sNext = (p < e) ? srcSorted[p] : 0;   // prefetch next index
    const _Float16* row = C + (size_t)s * NW;
    half4 v = *(const half4*)(row + 4 * lane);
    float spv = 0.f;
    if (lane < 8) spv = (float)row[512 + lane];
    a0 += (float)v[0]; a1 += (float)v[1]; a2 += (float)v[2]; a3 += (float)v[3];
    sp += spv;
  }
  const float inv = (cnt > 0) ? 1.f / (float)cnt : 0.f;
  const _Float16* self = C + (size_t)node * NW;
  half4 sv = *(const half4*)(self + 256 + 4 * lane);
  half4 zo;
  zo[0] = (_Float16)fmaxf(a0 * inv + blv.x + (float)sv[0], 0.f);
  zo[1] = (_Float16)fmaxf(a1 * inv + blv.y + (float)sv[1], 0.f);
  zo[2] = (_Float16)fmaxf(a2 * inv + blv.z + (float)sv[2], 0.f);
  zo[3] = (_Float16)fmaxf(a3 * inv + blv.w + (float)sv[3], 0.f);
  *(half4*)(Zh + (size_t)node * 256 + 4 * lane) = zo;

  float sval = 0.f;
  if (lane < 8) sval = sp * inv + bla[lane] + (float)self[520 + lane];
  float m = sval;
  m = fmaxf(m, __shfl_xor(m, 1));
  m = fmaxf(m, __shfl_xor(m, 2));
  m = fmaxf(m, __shfl_xor(m, 4));
  float ex = expf(sval - m);
  float su = ex;
  su += __shfl_xor(su, 1);
  su += __shfl_xor(su, 2);
  su += __shfl_xor(su, 4);
  if (lane < 8) Ss[(size_t)node * 8 + lane] = ex / su;
}

// ---------------- pool: per 125-node chunk: AggS (LDS) -> Ap partial + Xp partial ----------------
__global__ __launch_bounds__(256) void pool_kernel(
    const float* __restrict__ Ss, const _Float16* __restrict__ Zh,
    const int* __restrict__ offsets, const int* __restrict__ srcSorted,
    float* __restrict__ Xp, float* __restrict__ Ap)
{
  const int g = blockIdx.x >> 3;
  const int chunk = blockIdx.x & 7;
  const int n0 = g * NPG + chunk * 125;
  const int t = threadIdx.x;
  __shared__ float lSs[125][8];
  __shared__ float lAg[125][8];
  __shared__ float apTmp[4][64];

  if (t < 125) {
    const int node = n0 + t;
    float4 s0 = *(const float4*)&Ss[(size_t)node * 8];
    float4 s1 = *(const float4*)&Ss[(size_t)node * 8 + 4];
    lSs[t][0] = s0.x; lSs[t][1] = s0.y; lSs[t][2] = s0.z; lSs[t][3] = s0.w;
    lSs[t][4] = s1.x; lSs[t][5] = s1.y; lSs[t][6] = s1.z; lSs[t][7] = s1.w;
    float a[8] = {0.f, 0.f, 0.f, 0.f, 0.f, 0.f, 0.f, 0.f};
    const int b = offsets[node], e = offsets[node + 1];
    for (int p = b; p < e; ++p) {
      const int s = srcSorted[p];
      float4 v0 = *(const float4*)&Ss[(size_t)s * 8];
      float4 v1 = *(const float4*)&Ss[(size_t)s * 8 + 4];
      a[0] += v0.x; a[1] += v0.y; a[2] += v0.z; a[3] += v0.w;
      a[4] += v1.x; a[5] += v1.y; a[6] += v1.z; a[7] += v1.w;
    }
#pragma unroll
    for (int c = 0; c < 8; ++c) lAg[t][c] = a[c];
  }
  __syncthreads();
  {
    const int sl = t >> 6, i = (t >> 3) & 7, j = t & 7;
    float acc = 0.f;
    for (int n = sl; n < 125; n += 4) acc += lAg[n][i] * lSs[n][j];
    apTmp[sl][((i << 3) | j)] = acc;
  }
  __syncthreads();
  if (t < 64) atomicAdd(&Ap[g * 64 + t], apTmp[0][t] + apTmp[1][t] + apTmp[2][t] + apTmp[3][t]);
  float xc[8] = {0.f, 0.f, 0.f, 0.f, 0.f, 0.f, 0.f, 0.f};
  for (int n = 0; n < 125; ++n) {
    float zv = (float)Zh[(size_t)(n0 + n) * 256 + t];
#pragma unroll
    for (int c = 0; c < 8; ++c) xc[c] = fmaf(lSs[n][c], zv, xc[c]);
  }
#pragma unroll
  for (int c = 0; c < 8; ++c)
    atomicAdd(&Xp[((size_t)g * 8 + c) * 256 + t], xc[c]);
}

// ---------------- final: mask/deg -> agg -> Zp -> classifier -> out[g] ----------------
__global__ __launch_bounds__(1024) void final_kernel(
    const float* __restrict__ Xp, const float* __restrict__ Ap,
    const float* __restrict__ Wl2, const float* __restrict__ bl2,
    const float* __restrict__ Wr2, const float* __restrict__ Wc1,
    const float* __restrict__ bc1, const float* __restrict__ Wc2,
    const float* __restrict__ bc2, float* __restrict__ out)
{
  const int g = blockIdx.x;
  const int t = threadIdx.x;
  const int c = t & 255, q = t >> 8;
  __shared__ float lAp[64];
  __shared__ float lXp[8][256];
  __shared__ float lAgg[8][256];
  __shared__ float lG[2048];
  __shared__ float part[4][256];
  __shared__ float red[256];
  if (t < 64) lAp[t] = Ap[g * 64 + t];
  lXp[q][c]     = Xp[((size_t)g * 8 + q) * 256 + c];
  lXp[q + 4][c] = Xp[((size_t)g * 8 + q + 4) * 256 + c];
  __syncthreads();
#pragma unroll
  for (int jj = 0; jj < 2; ++jj) {
    int j = q + jj * 4;
    float d = 0.f, s = 0.f;
#pragma unroll
    for (int i = 0; i < 8; ++i) {
      bool m = (lAp[i * 8 + j] != 0.f);
      d += m ? 1.f : 0.f;
      s += m ? lXp[i][c] : 0.f;
    }
    lAgg[j][c] = (d > 0.f) ? s / fmaxf(d, 1.f) : 0.f;
  }
  __syncthreads();
#pragma unroll
  for (int jj = 0; jj < 2; ++jj) {
    int j = q + jj * 4;
    float az = bl2[c];
#pragma unroll 4
    for (int k = 0; k < 256; ++k) {
      az += lAgg[j][k] * Wl2[(size_t)k * 256 + c] + lXp[j][k] * Wr2[(size_t)k * 256 + c];
    }
    lG[j * 256 + c] = fmaxf(az, 0.f);
  }
  __syncthreads();
  float a = 0.f;
  const int kb = q * 512;
#pragma unroll 4
  for (int k = kb; k < kb + 512; ++k) a = fmaf(lG[k], Wc1[(size_t)k * 256 + c], a);
  part[q][c] = a;
  __syncthreads();
  if (t < 256) {
    float s = bc1[t] + part[0][t] + part[1][t] + part[2][t] + part[3][t];
    red[t] = fmaxf(s, 0.f) * Wc2[t];
  }
  __syncthreads();
  for (int off = 128; off > 0; off >>= 1) {
    if (t < off) red[t] += red[t + off];
    __syncthreads();
  }
  if (t == 0) out[g] = red[0] + bc2[0];
}

extern "C" void kernel_launch(void* const* d_in, const int* in_sizes, int n_in,
                              void* d_out, int out_size, void* d_ws, size_t ws_size,
                              hipStream_t stream) {
  const float* x   = (const float*)d_in[0];
  const int*   ei  = (const int*)d_in[1];
  const float* Wl1 = (const float*)d_in[3];
  const float* bl1 = (const float*)d_in[4];
  const float* Wr1 = (const float*)d_in[5];
  const float* Wla = (const float*)d_in[6];
  const float* bla = (const float*)d_in[7];
  const float* Wra = (const float*)d_in[8];
  const float* Wl2 = (const float*)d_in[9];
  const float* bl2 = (const float*)d_in[10];
  const float* Wr2 = (const float*)d_in[11];
  const float* Wc1 = (const float*)d_in[12];
  const float* bc1 = (const float*)d_in[13];
  const float* Wc2 = (const float*)d_in[14];
  const float* bc2 = (const float*)d_in[15];
  float* out = (float*)d_out;

  // workspace layout (~186 MB)
  _Float16* C    = (_Float16*)d_ws;                  // 32000*528
  _Float16* WsT2 = C + (size_t)32000 * NW;           // 540672
  _Float16* XH   = WsT2 + 540672;                    // 32000*1024
  _Float16* XL   = XH + (size_t)32000 * 1024;        // 32000*1024
  _Float16* Zh   = XL + (size_t)32000 * 1024;        // 32000*256
  float* Ss   = (float*)(Zh + (size_t)32000 * 256);  // 32000*8
  float* Xp   = Ss + 256000;                         // 32*8*256
  float* Ap   = Xp + 65536;                          // 32*64
  int* deg     = (int*)(Ap + 2048);                  // 32000
  int* cursor  = deg + 32000;                        // 32000
  int* offsets = cursor + 32000;                     // 32001
  int* srcS    = offsets + 32001;                    // 256000
  unsigned* zbuf = (unsigned*)Xp;                    // Xp+Ap+deg+cursor = 131584 words

  const int* src = ei;
  const int* dst = ei + N_EDGES;

  prep_kernel<<<dim3(3, 128), 256, 0, stream>>>(Wl1, Wr1, Wla, Wra, WsT2, zbuf);
  xsplit<<<16000, 256, 0, stream>>>(x, XH, XL);
  count_deg<<<1000, 256, 0, stream>>>(dst, deg);
  scan_kernel<<<1, 1024, 0, stream>>>(deg, offsets);
  scatter_kernel<<<1000, 256, 0, stream>>>(src, dst, offsets, cursor, srcS);
  gemm_mfma<<<1250, 256, 0, stream>>>(XH, XL, WsT2, C);
  aggregate_node<<<8000, 256, 0, stream>>>(C, offsets, srcS, bl1, bla, Zh, Ss);
  pool_kernel<<<256, 256, 0, stream>>>(Ss, Zh, offsets, srcS, Xp, Ap);
  final_kernel<<<32, 1024, 0, stream>>>(Xp, Ap, Wl2, bl2, Wr2, Wc1, bc1, Wc2, bc2, out);
}